// Round 1
// baseline (344.547 us; speedup 1.0000x reference)
//
#include <hip/hip_runtime.h>
#include <hip/hip_bf16.h>
#include <stdint.h>

typedef __bf16 bf16;
typedef __bf16 bf16x4 __attribute__((ext_vector_type(4)));
typedef __bf16 bf16x8 __attribute__((ext_vector_type(8)));
typedef float f32x4 __attribute__((ext_vector_type(4)));
typedef float f32x8 __attribute__((ext_vector_type(8)));

#define MFMA16 __builtin_amdgcn_mfma_f32_16x16x32_bf16

// async global->LDS, 16B per lane; LDS dest must be base + lane*16 pattern.
__device__ __forceinline__ void gload_lds16(void* lds, const void* g) {
  __builtin_amdgcn_global_load_lds(
      (const __attribute__((address_space(1))) unsigned int*)g,
      (__attribute__((address_space(3))) unsigned int*)lds, 16, 0, 0);
}

#define S_BARRIER() __builtin_amdgcn_s_barrier()
// rule #18: sched_barrier(0) right after an inline-asm lgkmcnt wait so MFMAs
// can't be hoisted above it.
#define WAIT_LGKM0()                                   \
  do {                                                 \
    asm volatile("s_waitcnt lgkmcnt(0)" ::: "memory"); \
    __builtin_amdgcn_sched_barrier(0);                 \
  } while (0)
#define WAIT_VM(n) asm volatile("s_waitcnt vmcnt(" #n ")" ::: "memory")

// ---------------------------------------------------------------------------
// fp32 -> bf16 converts (HBM-bound)
// ---------------------------------------------------------------------------
__global__ __launch_bounds__(256) void cvt3(
    const float* __restrict__ s0, const float* __restrict__ s1,
    const float* __restrict__ s2, bf16* __restrict__ d0,
    bf16* __restrict__ d1, bf16* __restrict__ d2) {
  const float* srcs[3] = {s0, s1, s2};
  bf16* dsts[3] = {d0, d1, d2};
  const float* src = srcs[blockIdx.y];
  bf16* dst = dsts[blockIdx.y];
  int i = (blockIdx.x * 256 + threadIdx.x) * 4;
  f32x4 v = *(const f32x4*)(src + i);
  bf16x4 o;
#pragma unroll
  for (int j = 0; j < 4; j++) o[j] = (bf16)v[j];
  *(bf16x4*)(dst + i) = o;
}

__global__ __launch_bounds__(256) void cvt1(const float* __restrict__ src,
                                            bf16* __restrict__ dst) {
  int i = (blockIdx.x * 256 + threadIdx.x) * 4;
  f32x4 v = *(const f32x4*)(src + i);
  bf16x4 o;
#pragma unroll
  for (int j = 0; j < 4; j++) o[j] = (bf16)v[j];
  *(bf16x4*)(dst + i) = o;
}

__global__ __launch_bounds__(256) void cvt4(const float* __restrict__ w0,
                                            const float* __restrict__ w1,
                                            const float* __restrict__ w2,
                                            const float* __restrict__ w3,
                                            bf16* __restrict__ dst) {
  const float* srcs[4] = {w0, w1, w2, w3};
  const float* src = srcs[blockIdx.y];
  int i = (blockIdx.x * 256 + threadIdx.x) * 4;
  f32x4 v = *(const f32x4*)(src + i);
  bf16x4 o;
#pragma unroll
  for (int j = 0; j < 4; j++) o[j] = (bf16)v[j];
  *(bf16x4*)(dst + (size_t)blockIdx.y * 1048576 + i) = o;
}

// ---------------------------------------------------------------------------
// 256x256 8-phase GEMM (T1+T2+T3+T4+T5 stack), K = 1024 fixed.
// C[m,n] = sum_k A[m,k]*W[n,k].  8 waves (2M x 4N), 512 threads.
// LDS 128 KiB: 2 dbuf x {A,B} x 2 halves x [128 rows][64 cols] bf16.
// Per-wave output 128x64, split across both staging halves so per-phase
// ds_reads align exactly with staging-half granularity:
//   M row  = (f>>2)*128 + wm2*64 + (f&3)*16 + quad*4 + r   (f = 0..7)
//   N col  = (g>>1)*128 + wn4*32 + (g&1)*16 + m16          (g = 0..3)
// Phase -> quadrant: ph1 Q00 (read A0:8 + B0:4), ph2 Q01 (read B1:4),
// ph3 Q11 (read A1:8), ph4 Q10 (regs only). Stage schedule (one half-tile
// per phase, 2x gload_lds16): ph1:(t+1).B1  ph2:(t+2).A0  ph3:(t+2).B0
// ph4:(t+2).A1  ph5:(t+2).B1  ph6:(t+3).A0  ph7:(t+3).B0  ph8:(t+3).A1.
// Every stage overwrites a region last read >=1 barrier earlier.
// vmcnt(6) at ph4/ph8 retires exactly the next K-tile's 4 half-tiles.
// XOR chunk swizzle (c ^= row&7) applied on the GLOBAL source of
// global_load_lds and again on ds_read (both-sides involution, rule #21).
// mode 0: C fp32 [8192,1024]; 1: [B,H,S,64] bf16; 2: [B,H,64,S] bf16.
// ---------------------------------------------------------------------------
__device__ __forceinline__ void gemm256_body(const bf16* __restrict__ A,
                                             const bf16* __restrict__ W,
                                             void* __restrict__ Craw, int mode,
                                             int m0, int n0, bf16* smem) {
  constexpr int K = 1024;
  const int t = threadIdx.x;
  const int lane = t & 63;
  const int m16 = lane & 15;
  const int quad = (lane >> 4) & 3;
  const int sw = m16 & 7;  // row&7 for all frag reads (row offsets are 8-mult)
  const int w = t >> 6;
  const int wm2 = (w >> 2) * 64;  // wave M sub-offset within a 128-row half
  const int wn4 = (w & 3) * 32;   // wave N sub-offset within a 128-row half

  const bf16* Ab = A + (size_t)m0 * K;
  const bf16* Bb = W + (size_t)n0 * K;

  // stage one half-tile (128 rows x 64 cols) into buf: 2 x 16B per thread.
  auto STG = [&](int buf, int isB, int half, int kt) {
    bf16* dst = smem + buf * 32768 + isB * 16384 + half * 8192;
    const bf16* src = (isB ? Bb : Ab) + (size_t)(half * 128) * K + kt * 64;
#pragma unroll
    for (int ld = 0; ld < 2; ld++) {
      int idx = ld * 512 + t;
      int row = idx >> 3;
      int c = (idx & 7) ^ (row & 7);  // pre-swizzled global chunk
      gload_lds16(dst + idx * 8, src + (size_t)row * K + c * 8);
    }
  };

  bf16x8 aR[8], bR0[4], bR1[4];

  auto LDA = [&](int buf, int half) {
    const bf16* As = smem + buf * 32768 + half * 8192;
#pragma unroll
    for (int f = 0; f < 4; f++)
#pragma unroll
      for (int ks = 0; ks < 2; ks++)
        aR[f * 2 + ks] = *(const bf16x8*)&As[(wm2 + f * 16 + m16) * 64 +
                                             (((ks * 4 + quad) ^ sw) * 8)];
  };
  auto LDB = [&](int buf, int half, bf16x8* bR) {
    const bf16* Bs = smem + buf * 32768 + 16384 + half * 8192;
#pragma unroll
    for (int g = 0; g < 2; g++)
#pragma unroll
      for (int ks = 0; ks < 2; ks++)
        bR[g * 2 + ks] = *(const bf16x8*)&Bs[(wn4 + g * 16 + m16) * 64 +
                                             (((ks * 4 + quad) ^ sw) * 8)];
  };

  f32x4 acc[8][4];
#pragma unroll
  for (int f = 0; f < 8; f++)
#pragma unroll
    for (int g = 0; g < 4; g++) acc[f][g] = (f32x4){0.f, 0.f, 0.f, 0.f};

  auto MM = [&](int mh, int nh, const bf16x8* bR) {
    __builtin_amdgcn_s_setprio(1);
#pragma unroll
    for (int f = 0; f < 4; f++)
#pragma unroll
      for (int g = 0; g < 2; g++)
#pragma unroll
        for (int ks = 0; ks < 2; ks++)
          acc[mh * 4 + f][nh * 2 + g] = MFMA16(
              aR[f * 2 + ks], bR[g * 2 + ks], acc[mh * 4 + f][nh * 2 + g],
              0, 0, 0);
    __builtin_amdgcn_s_setprio(0);
  };

  // ---- prologue: tile0 full (buf0) + tile1 A0,B0,A1 (buf1); land tile0.
  STG(0, 0, 0, 0);
  STG(0, 1, 0, 0);
  STG(0, 0, 1, 0);
  STG(0, 1, 1, 0);
  STG(1, 0, 0, 1);
  STG(1, 1, 0, 1);
  STG(1, 0, 1, 1);
  WAIT_VM(6);
  S_BARRIER();

  // ---- main loop: 2 K-tiles per iteration, 8 phases. K/64/2 - 1 = 7 full.
#pragma unroll 1
  for (int it = 0; it < 7; ++it) {
    int t2 = 2 * it + 2, t3 = 2 * it + 3;
    // ph1: Q00
    LDA(0, 0);
    LDB(0, 0, bR0);
    STG(1, 1, 1, 2 * it + 1);
    S_BARRIER();
    WAIT_LGKM0();
    MM(0, 0, bR0);
    S_BARRIER();
    // ph2: Q01
    LDB(0, 1, bR1);
    STG(0, 0, 0, t2);
    S_BARRIER();
    WAIT_LGKM0();
    MM(0, 1, bR1);
    S_BARRIER();
    // ph3: Q11
    LDA(0, 1);
    STG(0, 1, 0, t2);
    S_BARRIER();
    WAIT_LGKM0();
    MM(1, 1, bR1);
    S_BARRIER();
    // ph4: Q10 (regs only)
    STG(0, 0, 1, t2);
    S_BARRIER();
    MM(1, 0, bR0);
    WAIT_VM(6);  // retires all 4 half-tiles of tile 2it+1
    S_BARRIER();
    // ph5: Q00 on odd tile
    LDA(1, 0);
    LDB(1, 0, bR0);
    STG(0, 1, 1, t2);
    S_BARRIER();
    WAIT_LGKM0();
    MM(0, 0, bR0);
    S_BARRIER();
    // ph6: Q01
    LDB(1, 1, bR1);
    STG(1, 0, 0, t3);
    S_BARRIER();
    WAIT_LGKM0();
    MM(0, 1, bR1);
    S_BARRIER();
    // ph7: Q11
    LDA(1, 1);
    STG(1, 1, 0, t3);
    S_BARRIER();
    WAIT_LGKM0();
    MM(1, 1, bR1);
    S_BARRIER();
    // ph8: Q10
    STG(1, 0, 1, t3);
    S_BARRIER();
    MM(1, 0, bR0);
    WAIT_VM(6);  // retires all 4 half-tiles of tile 2it+2
    S_BARRIER();
  }

  // ---- peeled last iteration (tiles 14,15): only (15).B1 still to stage.
  LDA(0, 0);
  LDB(0, 0, bR0);
  STG(1, 1, 1, 15);
  S_BARRIER();
  WAIT_LGKM0();
  MM(0, 0, bR0);
  S_BARRIER();
  LDB(0, 1, bR1);
  S_BARRIER();
  WAIT_LGKM0();
  MM(0, 1, bR1);
  S_BARRIER();
  LDA(0, 1);
  S_BARRIER();
  WAIT_LGKM0();
  MM(1, 1, bR1);
  S_BARRIER();
  S_BARRIER();
  MM(1, 0, bR0);
  WAIT_VM(0);  // drain: tile15 fully landed
  S_BARRIER();
  LDA(1, 0);
  LDB(1, 0, bR0);
  S_BARRIER();
  WAIT_LGKM0();
  MM(0, 0, bR0);
  S_BARRIER();
  LDB(1, 1, bR1);
  S_BARRIER();
  WAIT_LGKM0();
  MM(0, 1, bR1);
  S_BARRIER();
  LDA(1, 1);
  S_BARRIER();
  WAIT_LGKM0();
  MM(1, 1, bR1);
  S_BARRIER();
  MM(1, 0, bR0);

  // ---- epilogue
#pragma unroll
  for (int f = 0; f < 8; f++) {
    int rbase = m0 + (f >> 2) * 128 + wm2 + (f & 3) * 16 + quad * 4;
#pragma unroll
    for (int g = 0; g < 4; g++) {
      int col = n0 + (g >> 1) * 128 + wn4 + (g & 1) * 16 + m16;
#pragma unroll
      for (int r = 0; r < 4; r++) {
        int row = rbase + r;
        if (mode == 0) {
          ((float*)Craw)[(size_t)row * 1024 + col] = acc[f][g][r];
        } else {
          int b = row >> 11, s = row & 2047;
          int h = col >> 6, d = col & 63;
          bf16 v = (bf16)acc[f][g][r];
          if (mode == 1)
            ((bf16*)Craw)[(((size_t)(b * 16 + h)) * 2048 + s) * 64 + d] = v;
          else
            ((bf16*)Craw)[(((size_t)(b * 16 + h)) * 64 + d) * 2048 + s] = v;
        }
      }
    }
  }
}

// Bijective XCD-aware remap for the 128-block (4n x 32m) grid: XCD x owns
// m-strips 4x..4x+3, all 4 n-blocks of a strip temporally adjacent -> each
// 512KB A-strip + the 2MB weight panel live in one per-XCD L2.
__device__ __forceinline__ void xcd_remap256(int& m0, int& n0) {
  int id = blockIdx.y * 4 + blockIdx.x;  // 0..127, nwg % 8 == 0
  int xcd = id & 7;
  int j = id >> 3;  // 0..15
  m0 = (xcd * 4 + (j >> 2)) * 256;
  n0 = (j & 3) * 256;
}

// Fused Q/K/V projections: grid (4, 32, 3), 512 thr. K/V s-strips fully
// beyond vl are never consumed -> early-exit (block-uniform, pre-barrier).
__global__ __launch_bounds__(512, 2) void gemm_qkv(
    const bf16* __restrict__ xq, const bf16* __restrict__ xk,
    const bf16* __restrict__ xv, const bf16* __restrict__ wb,
    const int* __restrict__ vlen, bf16* __restrict__ qp,
    bf16* __restrict__ kp, bf16* __restrict__ vt) {
  __shared__ bf16 smem[65536];  // 128 KiB
  int m0, n0;
  xcd_remap256(m0, n0);
  const int z = blockIdx.z;
  if (z >= 1) {
    int b = m0 >> 11;
    int s0 = m0 & 2047;
    int vl = vlen[b];
    if (vl != 0 && s0 >= vl) return;
  }
  const bf16* A = (z == 0) ? xq : (z == 1) ? xk : xv;
  const bf16* W = wb + (size_t)z * 1048576;
  bf16* C = (z == 0) ? qp : (z == 1) ? kp : vt;
  gemm256_body(A, W, C, (z == 2) ? 2 : 1, m0, n0, smem);
}

// Single GEMM (bf16 inputs): grid (4, 32), 512 thr.
__global__ __launch_bounds__(512, 2) void gemm_one256(
    const bf16* __restrict__ A, const bf16* __restrict__ W,
    void* __restrict__ Craw, int mode) {
  __shared__ bf16 smem[65536];
  int m0, n0;
  xcd_remap256(m0, n0);
  gemm256_body(A, W, Craw, mode, m0, n0, smem);
}

// Fallback GEMM with fp32 operands converted in staging (Tier C path).
template <int AF32, int WF32>
__global__ __launch_bounds__(256) void gemm_bt(const void* __restrict__ Araw,
                                               const void* __restrict__ Wraw,
                                               void* __restrict__ Craw,
                                               int mode) {
  constexpr int K = 1024;
  __shared__ bf16 As[128 * 32];
  __shared__ bf16 Bs[128 * 32];
  const int t = threadIdx.x;
  const int lane = t & 63;
  const int quad = lane >> 4;
  const int m16 = lane & 15;
  const int w = t >> 6;
  const int m0 = blockIdx.y * 128;
  const int n0 = blockIdx.x * 128;
  const int wm = (w >> 1) * 64;
  const int wn = (w & 1) * 64;

  f32x4 acc[4][4];
#pragma unroll
  for (int i = 0; i < 4; i++)
#pragma unroll
    for (int j = 0; j < 4; j++) acc[i][j] = (f32x4){0.f, 0.f, 0.f, 0.f};

  for (int kt = 0; kt < K / 32; kt++) {
    bf16x8 aR[2], bR[2];
#pragma unroll
    for (int p = 0; p < 2; p++) {
      int idx = p * 256 + t;
      int row = idx >> 2;
      int ce = (idx & 3) * 8;
      size_t aoff = (size_t)(m0 + row) * K + kt * 32 + ce;
      size_t boff = (size_t)(n0 + row) * K + kt * 32 + ce;
      if constexpr (AF32) {
        f32x8 av = *(const f32x8*)((const float*)Araw + aoff);
#pragma unroll
        for (int j = 0; j < 8; j++) aR[p][j] = (bf16)av[j];
      } else {
        aR[p] = *(const bf16x8*)((const bf16*)Araw + aoff);
      }
      if constexpr (WF32) {
        f32x8 bv = *(const f32x8*)((const float*)Wraw + boff);
#pragma unroll
        for (int j = 0; j < 8; j++) bR[p][j] = (bf16)bv[j];
      } else {
        bR[p] = *(const bf16x8*)((const bf16*)Wraw + boff);
      }
    }
    __syncthreads();
#pragma unroll
    for (int p = 0; p < 2; p++) {
      int idx = p * 256 + t;
      *(bf16x8*)&As[idx * 8] = aR[p];
      *(bf16x8*)&Bs[idx * 8] = bR[p];
    }
    __syncthreads();

    bf16x8 af[4], bfr[4];
#pragma unroll
    for (int i = 0; i < 4; i++) {
      af[i] = *(const bf16x8*)&As[(wm + i * 16 + m16) * 32 + quad * 8];
      bfr[i] = *(const bf16x8*)&Bs[(wn + i * 16 + m16) * 32 + quad * 8];
    }
#pragma unroll
    for (int i = 0; i < 4; i++)
#pragma unroll
      for (int j = 0; j < 4; j++)
        acc[i][j] = MFMA16(af[i], bfr[j], acc[i][j], 0, 0, 0);
  }

#pragma unroll
  for (int i = 0; i < 4; i++) {
    int rbase = m0 + wm + i * 16 + quad * 4;
#pragma unroll
    for (int j = 0; j < 4; j++) {
      int col = n0 + wn + j * 16 + m16;
#pragma unroll
      for (int r = 0; r < 4; r++) {
        int row = rbase + r;
        if (mode == 0) {
          ((float*)Craw)[(size_t)row * 1024 + col] = acc[i][j][r];
        } else {
          int b = row >> 11, s = row & 2047;
          int h = col >> 6, d = col & 63;
          bf16 v = (bf16)acc[i][j][r];
          if (mode == 1)
            ((bf16*)Craw)[(((size_t)(b * 16 + h)) * 2048 + s) * 64 + d] = v;
          else
            ((bf16*)Craw)[(((size_t)(b * 16 + h)) * 64 + d) * 2048 + s] = v;
        }
      }
    }
  }
}

// ---------------------------------------------------------------------------
// Flash attention, de-onlined softmax (fixed offset M=32):
//   p = exp(dot*0.125 - 32) = exp2(dot*0.18033688 - 46.166241)
// Masked keys: p = 0 exactly; vl==0: p = 1 (uniform softmax, matches ref).
// Wave owns 32 q-rows (2 A-frags) -> per-q-row K/V LDS traffic halved.
// Grid (S/128, B*H), 256 thr. qp/kp: [B,H,S,64]. vt: [B,H,64,S].
// K/V staged via global_load_lds with XOR chunk swizzle (global-side).
// Ps: per-wave 32x64 P tile, row stride 72 elems (2-way banks = free).
// ---------------------------------------------------------------------------
__global__ __launch_bounds__(256) void attn(const bf16* __restrict__ qp,
                                            const bf16* __restrict__ kp,
                                            const bf16* __restrict__ vt,
                                            const int* __restrict__ vlen,
                                            bf16* __restrict__ ctx) {
  __shared__ bf16 Ks[64 * 64];
  __shared__ bf16 Vs[64 * 64];
  __shared__ bf16 Ps[4 * 32 * 72];

  const int t = threadIdx.x;
  const int lane = t & 63;
  const int quad = lane >> 4;
  const int m16 = lane & 15;
  const int sw = m16 & 7;  // read-side XOR (row&7)
  const int w = t >> 6;
  const int bh = blockIdx.y;
  const int qt = blockIdx.x;
  const int b = bh >> 4;
  const int h = bh & 15;
  const int vl = vlen[b];

  const float C1 = 0.18033688f;  // 0.125 * log2(e)
  const float C2 = 46.166241f;   // 32 * log2(e)
  const float mArg = (vl == 0) ? 0.0f : -12800.0f;

  bf16x8 qf[2][2];
#pragma unroll
  for (int a = 0; a < 2; a++) {
    const bf16* qb =
        qp + ((size_t)(bh * 2048 + qt * 128 + w * 32 + a * 16 + m16)) * 64;
    qf[a][0] = *(const bf16x8*)(qb + quad * 8);
    qf[a][1] = *(const bf16x8*)(qb + 32 + quad * 8);
  }

  float rsum[2][4] = {{0.f, 0.f, 0.f, 0.f}, {0.f, 0.f, 0.f, 0.f}};
  f32x4 o[2][4];
#pragma unroll
  for (int a = 0; a < 2; a++)
#pragma unroll
    for (int nt = 0; nt < 4; nt++) o[a][nt] = (f32x4){0.f, 0.f, 0.f, 0.f};

  const int ktEnd = (vl == 0) ? 32 : ((vl + 63) >> 6);

  for (int kt = 0; kt < ktEnd; kt++) {
    __syncthreads();  // prior readers done
#pragma unroll
    for (int p = 0; p < 2; p++) {
      int idx = p * 256 + t;  // 16B chunk; rows are 128B (64 bf16)
      int row = idx >> 3;
      int gc = (idx & 7) ^ (row & 7);  // XOR swizzle in global address
      gload_lds16(&Ks[idx * 8],
                  &kp[((size_t)(bh * 2048 + kt * 64 + row)) * 64 + gc * 8]);
      gload_lds16(&Vs[idx * 8],
                  &vt[((size_t)(bh * 64 + row)) * 2048 + kt * 64 + gc * 8]);
    }
    __syncthreads();  // DMA drained, staged data visible

    // ---- QK^T: 2 q-subtiles share each K fragment
    f32x4 s[2][4];
#pragma unroll
    for (int a = 0; a < 2; a++)
#pragma unroll
      for (int nt = 0; nt < 4; nt++) s[a][nt] = (f32x4){0.f, 0.f, 0.f, 0.f};
#pragma unroll
    for (int nt = 0; nt < 4; nt++) {
      int key = nt * 16 + m16;
#pragma unroll
      for (int ks = 0; ks < 2; ks++) {
        bf16x8 kf =
            *(const bf16x8*)&Ks[key * 64 + (((ks * 4 + quad) ^ sw) * 8)];
        s[0][nt] = MFMA16(qf[0][ks], kf, s[0][nt], 0, 0, 0);
        s[1][nt] = MFMA16(qf[1][ks], kf, s[1][nt], 0, 0, 0);
      }
    }

    // ---- p = exp2(dot*C1 - C2); masked -> 0 (or 1 when vl==0)
#pragma unroll
    for (int nt = 0; nt < 4; nt++) {
      bool masked = (kt * 64 + nt * 16 + m16) >= vl;
#pragma unroll
      for (int a = 0; a < 2; a++)
#pragma unroll
        for (int r = 0; r < 4; r++) {
          float arg = masked ? mArg : (s[a][nt][r] * C1 - C2);
          bf16 pb = (bf16)__builtin_amdgcn_exp2f(arg);
          rsum[a][r] += (float)pb;
          Ps[w * 2304 + (a * 16 + quad * 4 + r) * 72 + nt * 16 + m16] = pb;
        }
    }

    // ---- PV: 2 q-subtiles share each V fragment (per-wave DS is in-order)
#pragma unroll
    for (int ks = 0; ks < 2; ks++) {
      bf16x8 pf0 = *(const bf16x8*)&Ps[w * 2304 + m16 * 72 + ks * 32 + quad * 8];
      bf16x8 pf1 =
          *(const bf16x8*)&Ps[w * 2304 + (16 + m16) * 72 + ks * 32 + quad * 8];
#pragma unroll
      for (int nt = 0; nt < 4; nt++) {
        int dh = nt * 16 + m16;
        bf16x8 vf =
            *(const bf16x8*)&Vs[dh * 64 + (((ks * 4 + quad) ^ sw) * 8)];
        o[0][nt] = MFMA16(pf0, vf, o[0][nt], 0, 0, 0);
        o[1][nt] = MFMA16(pf1, vf, o[1][nt], 0, 0, 0);
      }
    }
  }

  // ---- deferred row-sum reduction across the 16 key-lanes
#pragma unroll
  for (int off = 1; off < 16; off <<= 1)
#pragma unroll
    for (int a = 0; a < 2; a++)
#pragma unroll
      for (int r = 0; r < 4; r++) rsum[a][r] += __shfl_xor(rsum[a][r], off);
#pragma unroll
  for (int a = 0; a < 2; a++)
#pragma unroll
    for (int r = 0; r < 4; r++) rsum[a][r] = 1.0f / rsum[a][r];

  // ---- epilogue: normalize, merge heads into ctx [B,S,D]
#pragma unroll
  for (int a = 0; a < 2; a++)
#pragma unroll
    for (int nt = 0; nt < 4; nt++) {
      int dh = nt * 16 + m16;
#pragma unroll
      for (int r = 0; r < 4; r++) {
        int srow = qt * 128 + w * 32 + a * 16 + quad * 4 + r;
        ctx[((size_t)(b * 2048 + srow)) * 1024 + h * 64 + dh] =
            (bf16)(o[a][nt][r] * rsum[a][r]);
      }
    }
}

// ---------------------------------------------------------------------------
extern "C" void kernel_launch(void* const* d_in, const int* in_sizes, int n_in,
                              void* d_out, int out_size, void* d_ws,
                              size_t ws_size, hipStream_t stream) {
  const float* key = (const float*)d_in[0];
  const float* query = (const float*)d_in[1];
  const float* value = (const float*)d_in[2];
  const int* vlen = (const int*)d_in[3];
  const float* Wk = (const float*)d_in[4];
  const float* Wq = (const float*)d_in[5];
  const float* Wv = (const float*)d_in[6];
  const float* Wo = (const float*)d_in[7];

  const size_t NE = (size_t)4 * 2048 * 1024;  // 8,388,608 elems per tensor
  const size_t WE = 1048576;                  // weight elems

  const size_t needA = (6 * NE + 4 * WE) * sizeof(bf16);  // ~109.1 MB
  const size_t needB = (5 * NE + 4 * WE) * sizeof(bf16);  // ~92.3 MB
  dim3 gg(4, 32), gb(512), cb(256);

  if (ws_size >= needA) {
    // Tier A: separate activation buffers, fused QKV, vl-skip, 8-phase GEMM.
    bf16* qp = (bf16*)d_ws;
    bf16* kp = qp + NE;
    bf16* vt = kp + NE;
    bf16* xq = vt + NE;
    bf16* xk = xq + NE;
    bf16* xv = xk + NE;
    bf16* wb = xv + NE;
    bf16* ctx = xq;  // xq dead after gemm_qkv; reuse for attention output

    cvt4<<<dim3(1024, 4), cb, 0, stream>>>(Wq, Wk, Wv, Wo, wb);
    cvt3<<<dim3(8192, 3), cb, 0, stream>>>(query, key, value, xq, xk, xv);
    gemm_qkv<<<dim3(4, 32, 3), gb, 0, stream>>>(xq, xk, xv, wb, vlen, qp, kp,
                                                vt);
    attn<<<dim3(16, 64), cb, 0, stream>>>(qp, kp, vt, vlen, ctx);
    gemm_one256<<<gg, gb, 0, stream>>>(ctx, wb + 3 * WE, d_out, 0);
  } else if (ws_size >= needB) {
    // Tier B: single reused activation buffer.
    bf16* qp = (bf16*)d_ws;
    bf16* kp = qp + NE;
    bf16* vt = kp + NE;
    bf16* ctx = vt + NE;
    bf16* xb = ctx + NE;
    bf16* wb = xb + NE;

    cvt4<<<dim3(1024, 4), cb, 0, stream>>>(Wq, Wk, Wv, Wo, wb);
    cvt1<<<8192, cb, 0, stream>>>(query, xb);
    gemm_one256<<<gg, gb, 0, stream>>>(xb, wb + 0 * WE, qp, 1);
    cvt1<<<8192, cb, 0, stream>>>(key, xb);
    gemm_one256<<<gg, gb, 0, stream>>>(xb, wb + 1 * WE, kp, 1);
    cvt1<<<8192, cb, 0, stream>>>(value, xb);
    gemm_one256<<<gg, gb, 0, stream>>>(xb, wb + 2 * WE, vt, 2);
    attn<<<dim3(16, 64), cb, 0, stream>>>(qp, kp, vt, vlen, ctx);
    gemm_one256<<<gg, gb, 0, stream>>>(ctx, wb + 3 * WE, d_out, 0);
  } else {
    // Tier C: fp32 staging inside GEMM.
    bf16* qp = (bf16*)d_ws;
    bf16* kp = qp + NE;
    bf16* vt = kp + NE;
    bf16* ctx = vt + NE;
    dim3 g8(8, 64), b256(256);
    gemm_bt<1, 1><<<g8, b256, 0, stream>>>(query, Wq, qp, 1);
    gemm_bt<1, 1><<<g8, b256, 0, stream>>>(key, Wk, kp, 1);
    gemm_bt<1, 1><<<g8, b256, 0, stream>>>(value, Wv, vt, 2);
    attn<<<dim3(16, 64), b256, 0, stream>>>(qp, kp, vt, vlen, ctx);
    gemm_bt<0, 1><<<g8, b256, 0, stream>>>(ctx, Wo, d_out, 0);
  }
}

// Round 3
// 320.726 us; speedup vs baseline: 1.0743x; 1.0743x over previous
//
#include <hip/hip_runtime.h>
#include <hip/hip_bf16.h>
#include <stdint.h>

typedef __bf16 bf16;
typedef __bf16 bf16x4 __attribute__((ext_vector_type(4)));
typedef __bf16 bf16x8 __attribute__((ext_vector_type(8)));
typedef float f32x4 __attribute__((ext_vector_type(4)));
typedef float f32x8 __attribute__((ext_vector_type(8)));

#define MFMA16 __builtin_amdgcn_mfma_f32_16x16x32_bf16

// async global->LDS, 16B per lane; LDS dest must be base + lane*16 pattern.
__device__ __forceinline__ void gload_lds16(void* lds, const void* g) {
  __builtin_amdgcn_global_load_lds(
      (const __attribute__((address_space(1))) unsigned int*)g,
      (__attribute__((address_space(3))) unsigned int*)lds, 16, 0, 0);
}

#define S_BARRIER() __builtin_amdgcn_s_barrier()
// rule #18: sched_barrier(0) right after an inline-asm lgkmcnt wait so MFMAs
// can't be hoisted above it.
#define WAIT_LGKM0()                                   \
  do {                                                 \
    asm volatile("s_waitcnt lgkmcnt(0)" ::: "memory"); \
    __builtin_amdgcn_sched_barrier(0);                 \
  } while (0)
#define WAIT_VM(n) asm volatile("s_waitcnt vmcnt(" #n ")" ::: "memory")

// ---------------------------------------------------------------------------
// fp32 -> bf16 converts (HBM-bound)
// ---------------------------------------------------------------------------
__global__ __launch_bounds__(256) void cvt3(
    const float* __restrict__ s0, const float* __restrict__ s1,
    const float* __restrict__ s2, bf16* __restrict__ d0,
    bf16* __restrict__ d1, bf16* __restrict__ d2) {
  const float* srcs[3] = {s0, s1, s2};
  bf16* dsts[3] = {d0, d1, d2};
  const float* src = srcs[blockIdx.y];
  bf16* dst = dsts[blockIdx.y];
  int i = (blockIdx.x * 256 + threadIdx.x) * 4;
  f32x4 v = *(const f32x4*)(src + i);
  bf16x4 o;
#pragma unroll
  for (int j = 0; j < 4; j++) o[j] = (bf16)v[j];
  *(bf16x4*)(dst + i) = o;
}

__global__ __launch_bounds__(256) void cvt1(const float* __restrict__ src,
                                            bf16* __restrict__ dst) {
  int i = (blockIdx.x * 256 + threadIdx.x) * 4;
  f32x4 v = *(const f32x4*)(src + i);
  bf16x4 o;
#pragma unroll
  for (int j = 0; j < 4; j++) o[j] = (bf16)v[j];
  *(bf16x4*)(dst + i) = o;
}

__global__ __launch_bounds__(256) void cvt4(const float* __restrict__ w0,
                                            const float* __restrict__ w1,
                                            const float* __restrict__ w2,
                                            const float* __restrict__ w3,
                                            bf16* __restrict__ dst) {
  const float* srcs[4] = {w0, w1, w2, w3};
  const float* src = srcs[blockIdx.y];
  int i = (blockIdx.x * 256 + threadIdx.x) * 4;
  f32x4 v = *(const f32x4*)(src + i);
  bf16x4 o;
#pragma unroll
  for (int j = 0; j < 4; j++) o[j] = (bf16)v[j];
  *(bf16x4*)(dst + (size_t)blockIdx.y * 1048576 + i) = o;
}

// ---------------------------------------------------------------------------
// 128x256 fine-grained pipelined GEMM, K = 1024 fixed (16 K-tiles of 64).
// C[m,n] = sum_k A[m,k]*W[n,k].  8 waves (2M x 4N), 512 threads.
// Rationale (R1 post-mortem): 256^2 items are 46us quanta; 272 heavy items on
// 256 CUs -> makespan 2T regardless of scheduler. 128x256 quarters the
// quantum and gives Wo a perfect 256-item single round.
// LDS 144 KiB: 3 rotating bufs x (A 128x64 + B 256x64) bf16. Phase t:
//   LD(buf t%3): 16 ds_read_b128 -> STG tile t+2 into buf (t+2)%3 (6 gloads)
//   -> s_barrier -> lgkmcnt(0) -> 32 MFMA (setprio) -> vmcnt(6) -> s_barrier
// Ledger: vmcnt(6) retires exactly tile (t+1)'s 6 loads (issued phase t-1);
// stage target buf was last read phase t-1, whose closing barrier precedes
// this STG -> no WAR. Peel: phase14 vmcnt(0), phase15 no stage/no vm.
// XOR chunk swizzle (c ^= row&7) both-sides (global src + ds_read).
// mode 0: C fp32 [8192,1024]; 1: [B,H,S,64] bf16; 2: [B,H,64,S] bf16.
// ---------------------------------------------------------------------------
__device__ __forceinline__ void gemmF_body(const bf16* __restrict__ A,
                                           const bf16* __restrict__ W,
                                           void* __restrict__ Craw, int mode,
                                           int m0, int n0, bf16* smem) {
  constexpr int K = 1024;
  const int t = threadIdx.x;
  const int lane = t & 63;
  const int m16 = lane & 15;
  const int quad = (lane >> 4) & 3;
  const int sw = m16 & 7;  // row&7 for frag reads (row offsets are 16-mult)
  const int w = t >> 6;
  const int wm = (w >> 2) * 64;  // wave M offset (2 wave-rows)
  const int wn = (w & 3) * 64;   // wave N offset (4 wave-cols)

  const bf16* Ab = A + (size_t)m0 * K;
  const bf16* Bb = W + (size_t)n0 * K;

  // stage K-tile kt into buf: A 128x64 (2 rounds) + B 256x64 (4 rounds).
  auto STG = [&](int buf, int kt) {
    bf16* dA = smem + buf * 24576;
    bf16* dB = dA + 8192;
    const bf16* sA = Ab + kt * 64;
    const bf16* sB = Bb + kt * 64;
#pragma unroll
    for (int ld = 0; ld < 2; ld++) {
      int idx = ld * 512 + t;
      int row = idx >> 3;
      int c = (idx & 7) ^ (row & 7);  // pre-swizzled global chunk
      gload_lds16(dA + idx * 8, sA + (size_t)row * K + c * 8);
    }
#pragma unroll
    for (int ld = 0; ld < 4; ld++) {
      int idx = ld * 512 + t;
      int row = idx >> 3;
      int c = (idx & 7) ^ (row & 7);
      gload_lds16(dB + idx * 8, sB + (size_t)row * K + c * 8);
    }
  };

  bf16x8 aR[8], bR[8];
  auto LD = [&](int buf) {
    const bf16* As = smem + buf * 24576;
    const bf16* Bs = As + 8192;
#pragma unroll
    for (int f = 0; f < 4; f++)
#pragma unroll
      for (int ks = 0; ks < 2; ks++) {
        aR[f * 2 + ks] = *(const bf16x8*)&As[(wm + f * 16 + m16) * 64 +
                                             (((ks * 4 + quad) ^ sw) * 8)];
        bR[f * 2 + ks] = *(const bf16x8*)&Bs[(wn + f * 16 + m16) * 64 +
                                             (((ks * 4 + quad) ^ sw) * 8)];
      }
  };

  f32x4 acc[4][4];
#pragma unroll
  for (int f = 0; f < 4; f++)
#pragma unroll
    for (int g = 0; g < 4; g++) acc[f][g] = (f32x4){0.f, 0.f, 0.f, 0.f};

  auto MM = [&]() {
    __builtin_amdgcn_s_setprio(1);
#pragma unroll
    for (int f = 0; f < 4; f++)
#pragma unroll
      for (int g = 0; g < 4; g++)
#pragma unroll
        for (int ks = 0; ks < 2; ks++)
          acc[f][g] = MFMA16(aR[f * 2 + ks], bR[g * 2 + ks], acc[f][g], 0, 0, 0);
    __builtin_amdgcn_s_setprio(0);
  };

  // ---- prologue: stage tiles 0,1; retire tile0 (vmcnt leaves tile1's 6).
  STG(0, 0);
  STG(1, 1);
  WAIT_VM(6);
  S_BARRIER();

  int bufR = 0;
#pragma unroll 1
  for (int kt = 0; kt < 14; ++kt) {
    LD(bufR);
    int bufS = bufR + 2;
    if (bufS >= 3) bufS -= 3;
    STG(bufS, kt + 2);
    S_BARRIER();
    WAIT_LGKM0();
    MM();
    WAIT_VM(6);  // retires tile (kt+1)'s 6 loads; leaves tile (kt+2)'s
    S_BARRIER();
    bufR = (bufR + 1 == 3) ? 0 : bufR + 1;
  }
  // ---- phase 14: no stage; drain tile15 fully.
  LD(bufR);
  S_BARRIER();
  WAIT_LGKM0();
  MM();
  WAIT_VM(0);
  S_BARRIER();
  bufR = (bufR + 1 == 3) ? 0 : bufR + 1;
  // ---- phase 15: last tile.
  LD(bufR);
  S_BARRIER();
  WAIT_LGKM0();
  MM();

  // ---- epilogue
#pragma unroll
  for (int f = 0; f < 4; f++) {
    int rbase = m0 + wm + f * 16 + quad * 4;
#pragma unroll
    for (int g = 0; g < 4; g++) {
      int col = n0 + wn + g * 16 + m16;
#pragma unroll
      for (int r = 0; r < 4; r++) {
        int row = rbase + r;
        if (mode == 0) {
          ((float*)Craw)[(size_t)row * 1024 + col] = acc[f][g][r];
        } else {
          int b = row >> 11, s = row & 2047;
          int h = col >> 6, d = col & 63;
          bf16 v = (bf16)acc[f][g][r];
          if (mode == 1)
            ((bf16*)Craw)[(((size_t)(b * 16 + h)) * 2048 + s) * 64 + d] = v;
          else
            ((bf16*)Craw)[(((size_t)(b * 16 + h)) * 64 + d) * 2048 + s] = v;
        }
      }
    }
  }
}

// Fused Q/K/V projections: grid (4, 64, 3), 512 thr. Consecutive blockIdx.x
// share one 256KB A-strip (L2 temporal locality). K/V s-strips fully beyond
// vl early-exit pre-barrier; HW backfill absorbs them (fine granularity).
__global__ __launch_bounds__(512, 2) void gemm_qkv(
    const bf16* __restrict__ xq, const bf16* __restrict__ xk,
    const bf16* __restrict__ xv, const bf16* __restrict__ wb,
    const int* __restrict__ vlen, bf16* __restrict__ qp,
    bf16* __restrict__ kp, bf16* __restrict__ vt) {
  __shared__ bf16 smem[73728];  // 144 KiB
  const int m0 = blockIdx.y * 128;
  const int n0 = blockIdx.x * 256;
  const int z = blockIdx.z;
  if (z >= 1) {  // K/V: skip fully-masked s-strips (block-uniform)
    int b = m0 >> 11;
    int s0 = m0 & 2047;
    int vl = vlen[b];
    if (vl != 0 && s0 >= vl) return;
  }
  const bf16* A = (z == 0) ? xq : (z == 1) ? xk : xv;
  const bf16* W = wb + (size_t)z * 1048576;
  bf16* C = (z == 0) ? qp : (z == 1) ? kp : vt;
  gemmF_body(A, W, C, (z == 2) ? 2 : 1, m0, n0, smem);
}

// Single GEMM (bf16 inputs): grid (4, 64) = 256 items = one perfect round.
__global__ __launch_bounds__(512, 2) void gemm_one(const bf16* __restrict__ A,
                                                   const bf16* __restrict__ W,
                                                   void* __restrict__ Craw,
                                                   int mode) {
  __shared__ bf16 smem[73728];
  gemmF_body(A, W, Craw, mode, blockIdx.y * 128, blockIdx.x * 256, smem);
}

// Fallback GEMM with fp32 operands converted in staging (Tier C path).
template <int AF32, int WF32>
__global__ __launch_bounds__(256) void gemm_bt(const void* __restrict__ Araw,
                                               const void* __restrict__ Wraw,
                                               void* __restrict__ Craw,
                                               int mode) {
  constexpr int K = 1024;
  __shared__ bf16 As[128 * 32];
  __shared__ bf16 Bs[128 * 32];
  const int t = threadIdx.x;
  const int lane = t & 63;
  const int quad = lane >> 4;
  const int m16 = lane & 15;
  const int w = t >> 6;
  const int m0 = blockIdx.y * 128;
  const int n0 = blockIdx.x * 128;
  const int wm = (w >> 1) * 64;
  const int wn = (w & 1) * 64;

  f32x4 acc[4][4];
#pragma unroll
  for (int i = 0; i < 4; i++)
#pragma unroll
    for (int j = 0; j < 4; j++) acc[i][j] = (f32x4){0.f, 0.f, 0.f, 0.f};

  for (int kt = 0; kt < K / 32; kt++) {
    bf16x8 aR[2], bR[2];
#pragma unroll
    for (int p = 0; p < 2; p++) {
      int idx = p * 256 + t;
      int row = idx >> 2;
      int ce = (idx & 3) * 8;
      size_t aoff = (size_t)(m0 + row) * K + kt * 32 + ce;
      size_t boff = (size_t)(n0 + row) * K + kt * 32 + ce;
      if constexpr (AF32) {
        f32x8 av = *(const f32x8*)((const float*)Araw + aoff);
#pragma unroll
        for (int j = 0; j < 8; j++) aR[p][j] = (bf16)av[j];
      } else {
        aR[p] = *(const bf16x8*)((const bf16*)Araw + aoff);
      }
      if constexpr (WF32) {
        f32x8 bv = *(const f32x8*)((const float*)Wraw + boff);
#pragma unroll
        for (int j = 0; j < 8; j++) bR[p][j] = (bf16)bv[j];
      } else {
        bR[p] = *(const bf16x8*)((const bf16*)Wraw + boff);
      }
    }
    __syncthreads();
#pragma unroll
    for (int p = 0; p < 2; p++) {
      int idx = p * 256 + t;
      *(bf16x8*)&As[idx * 8] = aR[p];
      *(bf16x8*)&Bs[idx * 8] = bR[p];
    }
    __syncthreads();

    bf16x8 af[4], bfr[4];
#pragma unroll
    for (int i = 0; i < 4; i++) {
      af[i] = *(const bf16x8*)&As[(wm + i * 16 + m16) * 32 + quad * 8];
      bfr[i] = *(const bf16x8*)&Bs[(wn + i * 16 + m16) * 32 + quad * 8];
    }
#pragma unroll
    for (int i = 0; i < 4; i++)
#pragma unroll
      for (int j = 0; j < 4; j++)
        acc[i][j] = MFMA16(af[i], bfr[j], acc[i][j], 0, 0, 0);
  }

#pragma unroll
  for (int i = 0; i < 4; i++) {
    int rbase = m0 + wm + i * 16 + quad * 4;
#pragma unroll
    for (int j = 0; j < 4; j++) {
      int col = n0 + wn + j * 16 + m16;
#pragma unroll
      for (int r = 0; r < 4; r++) {
        int row = rbase + r;
        if (mode == 0) {
          ((float*)Craw)[(size_t)row * 1024 + col] = acc[i][j][r];
        } else {
          int b = row >> 11, s = row & 2047;
          int h = col >> 6, d = col & 63;
          bf16 v = (bf16)acc[i][j][r];
          if (mode == 1)
            ((bf16*)Craw)[(((size_t)(b * 16 + h)) * 2048 + s) * 64 + d] = v;
          else
            ((bf16*)Craw)[(((size_t)(b * 16 + h)) * 64 + d) * 2048 + s] = v;
        }
      }
    }
  }
}

// ---------------------------------------------------------------------------
// Flash attention, de-onlined softmax (fixed offset M=32):
//   p = exp(dot*0.125 - 32) = exp2(dot*0.18033688 - 46.166241)
// Masked keys: p = 0 exactly; vl==0: p = 1 (uniform softmax, matches ref).
// Wave owns 32 q-rows (2 A-frags) -> per-q-row K/V LDS traffic halved.
// Grid (S/128, B*H), 256 thr. qp/kp: [B,H,S,64]. vt: [B,H,64,S].
// K/V staged via global_load_lds with XOR chunk swizzle (global-side).
// Ps: per-wave 32x64 P tile, row stride 72 elems (2-way banks = free).
// ---------------------------------------------------------------------------
__global__ __launch_bounds__(256) void attn(const bf16* __restrict__ qp,
                                            const bf16* __restrict__ kp,
                                            const bf16* __restrict__ vt,
                                            const int* __restrict__ vlen,
                                            bf16* __restrict__ ctx) {
  __shared__ bf16 Ks[64 * 64];
  __shared__ bf16 Vs[64 * 64];
  __shared__ bf16 Ps[4 * 32 * 72];

  const int t = threadIdx.x;
  const int lane = t & 63;
  const int quad = lane >> 4;
  const int m16 = lane & 15;
  const int sw = m16 & 7;  // read-side XOR (row&7)
  const int w = t >> 6;
  const int bh = blockIdx.y;
  const int qt = blockIdx.x;
  const int b = bh >> 4;
  const int h = bh & 15;
  const int vl = vlen[b];

  const float C1 = 0.18033688f;  // 0.125 * log2(e)
  const float C2 = 46.166241f;   // 32 * log2(e)
  const float mArg = (vl == 0) ? 0.0f : -12800.0f;

  bf16x8 qf[2][2];
#pragma unroll
  for (int a = 0; a < 2; a++) {
    const bf16* qb =
        qp + ((size_t)(bh * 2048 + qt * 128 + w * 32 + a * 16 + m16)) * 64;
    qf[a][0] = *(const bf16x8*)(qb + quad * 8);
    qf[a][1] = *(const bf16x8*)(qb + 32 + quad * 8);
  }

  float rsum[2][4] = {{0.f, 0.f, 0.f, 0.f}, {0.f, 0.f, 0.f, 0.f}};
  f32x4 o[2][4];
#pragma unroll
  for (int a = 0; a < 2; a++)
#pragma unroll
    for (int nt = 0; nt < 4; nt++) o[a][nt] = (f32x4){0.f, 0.f, 0.f, 0.f};

  const int ktEnd = (vl == 0) ? 32 : ((vl + 63) >> 6);

  for (int kt = 0; kt < ktEnd; kt++) {
    __syncthreads();  // prior readers done
#pragma unroll
    for (int p = 0; p < 2; p++) {
      int idx = p * 256 + t;  // 16B chunk; rows are 128B (64 bf16)
      int row = idx >> 3;
      int gc = (idx & 7) ^ (row & 7);  // XOR swizzle in global address
      gload_lds16(&Ks[idx * 8],
                  &kp[((size_t)(bh * 2048 + kt * 64 + row)) * 64 + gc * 8]);
      gload_lds16(&Vs[idx * 8],
                  &vt[((size_t)(bh * 64 + row)) * 2048 + kt * 64 + gc * 8]);
    }
    __syncthreads();  // DMA drained, staged data visible

    // ---- QK^T: 2 q-subtiles share each K fragment
    f32x4 s[2][4];
#pragma unroll
    for (int a = 0; a < 2; a++)
#pragma unroll
      for (int nt = 0; nt < 4; nt++) s[a][nt] = (f32x4){0.f, 0.f, 0.f, 0.f};
#pragma unroll
    for (int nt = 0; nt < 4; nt++) {
      int key = nt * 16 + m16;
#pragma unroll
      for (int ks = 0; ks < 2; ks++) {
        bf16x8 kf =
            *(const bf16x8*)&Ks[key * 64 + (((ks * 4 + quad) ^ sw) * 8)];
        s[0][nt] = MFMA16(qf[0][ks], kf, s[0][nt], 0, 0, 0);
        s[1][nt] = MFMA16(qf[1][ks], kf, s[1][nt], 0, 0, 0);
      }
    }

    // ---- p = exp2(dot*C1 - C2); masked -> 0 (or 1 when vl==0)
#pragma unroll
    for (int nt = 0; nt < 4; nt++) {
      bool masked = (kt * 64 + nt * 16 + m16) >= vl;
#pragma unroll
      for (int a = 0; a < 2; a++)
#pragma unroll
        for (int r = 0; r < 4; r++) {
          float arg = masked ? mArg : (s[a][nt][r] * C1 - C2);
          bf16 pb = (bf16)__builtin_amdgcn_exp2f(arg);
          rsum[a][r] += (float)pb;
          Ps[w * 2304 + (a * 16 + quad * 4 + r) * 72 + nt * 16 + m16] = pb;
        }
    }

    // ---- PV: 2 q-subtiles share each V fragment (per-wave DS is in-order)
#pragma unroll
    for (int ks = 0; ks < 2; ks++) {
      bf16x8 pf0 = *(const bf16x8*)&Ps[w * 2304 + m16 * 72 + ks * 32 + quad * 8];
      bf16x8 pf1 =
          *(const bf16x8*)&Ps[w * 2304 + (16 + m16) * 72 + ks * 32 + quad * 8];
#pragma unroll
      for (int nt = 0; nt < 4; nt++) {
        int dh = nt * 16 + m16;
        bf16x8 vf =
            *(const bf16x8*)&Vs[dh * 64 + (((ks * 4 + quad) ^ sw) * 8)];
        o[0][nt] = MFMA16(pf0, vf, o[0][nt], 0, 0, 0);
        o[1][nt] = MFMA16(pf1, vf, o[1][nt], 0, 0, 0);
      }
    }
  }

  // ---- deferred row-sum reduction across the 16 key-lanes
#pragma unroll
  for (int off = 1; off < 16; off <<= 1)
#pragma unroll
    for (int a = 0; a < 2; a++)
#pragma unroll
      for (int r = 0; r < 4; r++) rsum[a][r] += __shfl_xor(rsum[a][r], off);
#pragma unroll
  for (int a = 0; a < 2; a++)
#pragma unroll
    for (int r = 0; r < 4; r++) rsum[a][r] = 1.0f / rsum[a][r];

  // ---- epilogue: normalize, merge heads into ctx [B,S,D]
#pragma unroll
  for (int a = 0; a < 2; a++)
#pragma unroll
    for (int nt = 0; nt < 4; nt++) {
      int dh = nt * 16 + m16;
#pragma unroll
      for (int r = 0; r < 4; r++) {
        int srow = qt * 128 + w * 32 + a * 16 + quad * 4 + r;
        ctx[((size_t)(b * 2048 + srow)) * 1024 + h * 64 + dh] =
            (bf16)(o[a][nt][r] * rsum[a][r]);
      }
    }
}

// ---------------------------------------------------------------------------
extern "C" void kernel_launch(void* const* d_in, const int* in_sizes, int n_in,
                              void* d_out, int out_size, void* d_ws,
                              size_t ws_size, hipStream_t stream) {
  const float* key = (const float*)d_in[0];
  const float* query = (const float*)d_in[1];
  const float* value = (const float*)d_in[2];
  const int* vlen = (const int*)d_in[3];
  const float* Wk = (const float*)d_in[4];
  const float* Wq = (const float*)d_in[5];
  const float* Wv = (const float*)d_in[6];
  const float* Wo = (const float*)d_in[7];

  const size_t NE = (size_t)4 * 2048 * 1024;  // 8,388,608 elems per tensor
  const size_t WE = 1048576;                  // weight elems

  const size_t needA = (6 * NE + 4 * WE) * sizeof(bf16);  // ~109.1 MB
  const size_t needB = (5 * NE + 4 * WE) * sizeof(bf16);  // ~92.3 MB
  dim3 gg(4, 64), gb(512), cb(256);

  if (ws_size >= needA) {
    // Tier A: separate activation buffers, fused QKV, vl-skip, fine tiles.
    bf16* qp = (bf16*)d_ws;
    bf16* kp = qp + NE;
    bf16* vt = kp + NE;
    bf16* xq = vt + NE;
    bf16* xk = xq + NE;
    bf16* xv = xk + NE;
    bf16* wb = xv + NE;
    bf16* ctx = xq;  // xq dead after gemm_qkv; reuse for attention output

    cvt4<<<dim3(1024, 4), cb, 0, stream>>>(Wq, Wk, Wv, Wo, wb);
    cvt3<<<dim3(8192, 3), cb, 0, stream>>>(query, key, value, xq, xk, xv);
    gemm_qkv<<<dim3(4, 64, 3), gb, 0, stream>>>(xq, xk, xv, wb, vlen, qp, kp,
                                                vt);
    attn<<<dim3(16, 64), cb, 0, stream>>>(qp, kp, vt, vlen, ctx);
    gemm_one<<<gg, gb, 0, stream>>>(ctx, wb + 3 * WE, d_out, 0);
  } else if (ws_size >= needB) {
    // Tier B: single reused activation buffer.
    bf16* qp = (bf16*)d_ws;
    bf16* kp = qp + NE;
    bf16* vt = kp + NE;
    bf16* ctx = vt + NE;
    bf16* xb = ctx + NE;
    bf16* wb = xb + NE;

    cvt4<<<dim3(1024, 4), cb, 0, stream>>>(Wq, Wk, Wv, Wo, wb);
    cvt1<<<8192, cb, 0, stream>>>(query, xb);
    gemm_one<<<gg, gb, 0, stream>>>(xb, wb + 0 * WE, qp, 1);
    cvt1<<<8192, cb, 0, stream>>>(key, xb);
    gemm_one<<<gg, gb, 0, stream>>>(xb, wb + 1 * WE, kp, 1);
    cvt1<<<8192, cb, 0, stream>>>(value, xb);
    gemm_one<<<gg, gb, 0, stream>>>(xb, wb + 2 * WE, vt, 2);
    attn<<<dim3(16, 64), cb, 0, stream>>>(qp, kp, vt, vlen, ctx);
    gemm_one<<<gg, gb, 0, stream>>>(ctx, wb + 3 * WE, d_out, 0);
  } else {
    // Tier C: fp32 staging inside GEMM.
    bf16* qp = (bf16*)d_ws;
    bf16* kp = qp + NE;
    bf16* vt = kp + NE;
    bf16* ctx = vt + NE;
    dim3 g8(8, 64), b256(256);
    gemm_bt<1, 1><<<g8, b256, 0, stream>>>(query, Wq, qp, 1);
    gemm_bt<1, 1><<<g8, b256, 0, stream>>>(key, Wk, kp, 1);
    gemm_bt<1, 1><<<g8, b256, 0, stream>>>(value, Wv, vt, 2);
    attn<<<dim3(16, 64), b256, 0, stream>>>(qp, kp, vt, vlen, ctx);
    gemm_bt<0, 1><<<g8, b256, 0, stream>>>(ctx, Wo, d_out, 0);
  }
}